// Round 8
// baseline (2496.982 us; speedup 1.0000x reference)
//
#include <hip/hip_runtime.h>

#define NN 200000
#define NB 128
#define NWG ((NN + NB - 1) / NB)   // 1563

typedef unsigned short u16;
typedef unsigned int u32;
typedef __attribute__((ext_vector_type(8))) short short8;
typedef __attribute__((ext_vector_type(4))) float f32x4;

#define LOG2E 1.4426950408889634f
#define TWOLOG2E 2.8853900817779268f

__device__ __forceinline__ u16 f2bf(float x) {
  u32 u = __float_as_uint(x);
  u += 0x7FFFu + ((u >> 16) & 1u);
  return (u16)(u >> 16);
}

// msg[n][k] = bf16(feat[n][k] / out_norm[n]); 16 threads per row, 8 elems each
__global__ void k_prep_msg(const float* __restrict__ feat, const float* __restrict__ onorm,
                           u16* __restrict__ msg) {
  int i = blockIdx.x * 256 + threadIdx.x;   // 3,200,000 total, exact
  int row = i >> 4, c8 = (i & 15) * 8;
  const float4 a = *(const float4*)(feat + (size_t)row * 128 + c8);
  const float4 b = *(const float4*)(feat + (size_t)row * 128 + c8 + 4);
  float s = 1.0f / onorm[row];
  short8 v = { (short)f2bf(a.x * s), (short)f2bf(a.y * s), (short)f2bf(a.z * s), (short)f2bf(a.w * s),
               (short)f2bf(b.x * s), (short)f2bf(b.y * s), (short)f2bf(b.z * s), (short)f2bf(b.w * s) };
  *(short8*)(msg + (size_t)row * 128 + c8) = v;
}

// Weights with the gate nonlinearity scale FOLDED IN:
//  gates i,f,o: x * -log2(e)  (sigmoid via exp2);  gate g: x * 2*log2(e)
__global__ void k_prep_w(const float* __restrict__ Wih, const float* __restrict__ Whh,
                         const float* __restrict__ Wlin, const float* __restrict__ bih,
                         const float* __restrict__ bhh, u16* __restrict__ wihb,
                         u16* __restrict__ whhb, u16* __restrict__ wlinb,
                         float* __restrict__ bsum) {
  int i = blockIdx.x * 256 + threadIdx.x;   // 147,968 total, exact
  if (i < 65536) {
    int gate = i >> 14;
    float s = (gate == 2) ? TWOLOG2E : -LOG2E;
    wihb[i] = f2bf(Wih[i] * s);
  } else if (i < 131072) {
    int j = i - 65536;
    int gate = j >> 14;
    float s = (gate == 2) ? TWOLOG2E : -LOG2E;
    whhb[j] = f2bf(Whh[j] * s);
  } else if (i < 147456) {
    wlinb[i - 131072] = f2bf(Wlin[i - 131072]);
  } else {
    int j = i - 147456;   // 0..511
    float s = ((j >> 7) == 2) ? TWOLOG2E : -LOG2E;
    bsum[j] = (bih[j] + bhh[j]) * s;
  }
}

__global__ void k_hist(const int* __restrict__ degs, int* __restrict__ hist, int n) {
  __shared__ int lh[33];
  if (threadIdx.x < 33) lh[threadIdx.x] = 0;
  __syncthreads();
  int i = blockIdx.x * 256 + threadIdx.x;
  if (i < n) atomicAdd(&lh[degs[i]], 1);
  __syncthreads();
  if (threadIdx.x < 33 && lh[threadIdx.x]) atomicAdd(&hist[threadIdx.x], lh[threadIdx.x]);
}

__global__ void k_scan(const int* __restrict__ hist, int* __restrict__ basep) {
  if (threadIdx.x == 0 && blockIdx.x == 0) {
    int a = 0;
    for (int d = 32; d >= 1; --d) { basep[d] = a; a += hist[d]; }
    basep[0] = a;
  }
}

__global__ void k_scatter(const int* __restrict__ degs, int* __restrict__ basep,
                          int* __restrict__ perm, int n) {
  __shared__ int lh[33], lbase[33], lc[33];
  int t = threadIdx.x;
  if (t < 33) { lh[t] = 0; lc[t] = 0; }
  __syncthreads();
  int i = blockIdx.x * 256 + t;
  int d = (i < n) ? degs[i] : 0;
  if (i < n) atomicAdd(&lh[d], 1);
  __syncthreads();
  if (t < 33 && lh[t]) lbase[t] = atomicAdd(&basep[t], lh[t]);
  __syncthreads();
  if (i < n) { int r = atomicAdd(&lc[d], 1); perm[lbase[d] + r] = i; }
}

// NB=128, 8 fine-grained passes of {32 MFMA -> 4-cell epilogue} per step.
// Rationale: MFMA pipe work is ~5k cyc/64-node-step (irreducible at 2075 TF
// ceiling) but the pipe idled 2/3 of the time in the 2-pass structure.
// Fine pass granularity + setprio lets the 2 waves/SIMD self-stagger so one
// wave's epilogue hides under the other's MFMAs; NB=128 halves step count.
__global__ __launch_bounds__(512, 2) void k_main(
    const u16* __restrict__ msg, const u16* __restrict__ wihb,
    const u16* __restrict__ whhb, const u16* __restrict__ wlinb,
    const float* __restrict__ bsum, const float* __restrict__ blin,
    const float* __restrict__ inorm, const int* __restrict__ nbrs,
    const int* __restrict__ degs, const int* __restrict__ perm,
    float* __restrict__ out) {
  __shared__ alignas(16) u16 Xl[2][128 * 136];   // 2 x 34816 B
  __shared__ alignas(16) u16 Hl[2][128 * 136];   // 2 x 34816 B
  __shared__ int gidl[128];                       // total ~139.8 KB

  const int tid = threadIdx.x;
  const int w = tid >> 6;
  const int lane = tid & 63;
  const int l15 = lane & 15;
  const int g4 = lane >> 4;
  const int w16 = w * 16;
  const int gr = tid >> 4;         // gather rows gr, gr+32, gr+64, gr+96
  const int gc = (tid & 15) * 8;
  const int base = blockIdx.x * NB;

  if (tid < NB) {
    int idx = base + tid;
    gidl[tid] = perm[idx < NN ? idx : NN - 1];   // tail block: clamp to the
  }                                              // global min-degree node;
  // duplicate slots compute identical values -> identical out writes (safe)
  {
    u32* hz = (u32*)Hl[0];   // 8704 u32 = 17*512, exact
#pragma unroll
    for (int s = 0; s < 17; ++s) hz[tid + s * 512] = 0;
  }
  __syncthreads();

  const int gid0 = gidl[gr], gid1 = gidl[gr + 32];
  const int gid2 = gidl[gr + 64], gid3 = gidl[gr + 96];
  const int* nb0 = nbrs + (size_t)gid0 * 32;
  const int* nb1 = nbrs + (size_t)gid1 * 32;
  const int* nb2 = nbrs + (size_t)gid2 * 32;
  const int* nb3 = nbrs + (size_t)gid3 * 32;

  // per-wave B fragments (row-major W rows are exactly the B-frag layout)
  short8 fih[4][4], fhh[4][4];
#pragma unroll
  for (int g = 0; g < 4; ++g)
#pragma unroll
    for (int kk = 0; kk < 4; ++kk) {
      size_t o = (size_t)(g * 128 + w16 + l15) * 128 + kk * 32 + g4 * 8;
      fih[g][kk] = *(const short8*)(wihb + o);
      fhh[g][kk] = *(const short8*)(whhb + o);
    }
  float bias[4];
#pragma unroll
  for (int g = 0; g < 4; ++g) bias[g] = bsum[g * 128 + w16 + l15];

  u32 dgp[8];
#pragma unroll
  for (int r = 0; r < 8; ++r) {
    u32 p = 0;
#pragma unroll
    for (int q = 0; q < 4; ++q) p |= ((u32)degs[gidl[r * 16 + g4 * 4 + q]]) << (8 * q);
    dgp[r] = p;
  }
  const int maxdeg = degs[gidl[0]];   // sorted descending -> first is WG max

  // prologue: gather + commit X(0) (one-time stall is fine)
  {
    int i0 = nb0[0], i1 = nb1[0], i2 = nb2[0], i3 = nb3[0];
    short8 p0 = *(const short8*)(msg + (size_t)i0 * 128 + gc);
    short8 p1 = *(const short8*)(msg + (size_t)i1 * 128 + gc);
    short8 p2 = *(const short8*)(msg + (size_t)i2 * 128 + gc);
    short8 p3 = *(const short8*)(msg + (size_t)i3 * 128 + gc);
    *(short8*)(&Xl[0][gr * 136 + gc]) = p0;
    *(short8*)(&Xl[0][(gr + 32) * 136 + gc]) = p1;
    *(short8*)(&Xl[0][(gr + 64) * 136 + gc]) = p2;
    *(short8*)(&Xl[0][(gr + 96) * 136 + gc]) = p3;
  }
  int ni0 = 0, ni1 = 0, ni2 = 0, ni3 = 0;
  if (maxdeg > 1) { ni0 = nb0[1]; ni1 = nb1[1]; ni2 = nb2[1]; ni3 = nb3[1]; }

  float c[8][4] = {};
  u32 hpk[8][2] = {};   // packed bf16 h carry (for inactive cells)
  __syncthreads();

  int cur = 0;
  for (int t = 0; t < maxdeg; ++t) {
    const int nxt = cur ^ 1;
    const bool more = (t + 1 < maxdeg);
    short8 pf0, pf1, pf2, pf3;
    if (more) {   // issue first half of next-step gather; commits at pass 1
      pf0 = *(const short8*)(msg + (size_t)ni0 * 128 + gc);
      pf1 = *(const short8*)(msg + (size_t)ni1 * 128 + gc);
    }
    const u16* Xc = &Xl[cur][0];
    const u16* Hc = &Hl[cur][0];
    u16* Xn = &Xl[nxt][0];
    u16* Hn = &Hl[nxt][0];

#pragma unroll
    for (int rf = 0; rf < 8; ++rf) {
      f32x4 acc[4];
#pragma unroll
      for (int g = 0; g < 4; ++g) acc[g] = (f32x4){bias[g], bias[g], bias[g], bias[g]};

      __builtin_amdgcn_s_setprio(1);
      {
        short8 ax[4];
#pragma unroll
        for (int kk = 0; kk < 4; ++kk)
          ax[kk] = *(const short8*)(&Xc[(rf * 16 + l15) * 136 + kk * 32 + g4 * 8]);
#pragma unroll
        for (int kk = 0; kk < 4; ++kk)
#pragma unroll
          for (int g = 0; g < 4; ++g)
            acc[g] = __builtin_amdgcn_mfma_f32_16x16x32_bf16(ax[kk], fih[g][kk], acc[g], 0, 0, 0);
      }
      {
        short8 ah[4];
#pragma unroll
        for (int kk = 0; kk < 4; ++kk)
          ah[kk] = *(const short8*)(&Hc[(rf * 16 + l15) * 136 + kk * 32 + g4 * 8]);
#pragma unroll
        for (int kk = 0; kk < 4; ++kk)
#pragma unroll
          for (int g = 0; g < 4; ++g)
            acc[g] = __builtin_amdgcn_mfma_f32_16x16x32_bf16(ah[kk], fhh[g][kk], acc[g], 0, 0, 0);
      }
      __builtin_amdgcn_s_setprio(0);

      // staged gather/commit hooks (latency hides under surrounding passes)
      if (rf == 1 && more) {
        *(short8*)(&Xn[gr * 136 + gc]) = pf0;
        *(short8*)(&Xn[(gr + 32) * 136 + gc]) = pf1;
        pf2 = *(const short8*)(msg + (size_t)ni2 * 128 + gc);
        pf3 = *(const short8*)(msg + (size_t)ni3 * 128 + gc);
      }
      if (rf == 4) {
        if (more) {
          *(short8*)(&Xn[(gr + 64) * 136 + gc]) = pf2;
          *(short8*)(&Xn[(gr + 96) * 136 + gc]) = pf3;
        }
        if (t + 2 < maxdeg) {
          ni0 = nb0[t + 2]; ni1 = nb1[t + 2]; ni2 = nb2[t + 2]; ni3 = nb3[t + 2];
        }
      }

      // epilogue for this pass: 4 cells, preacts pre-scaled
      //  sig(x)=rcp(1+exp2(x')); tanh(x)=(exp2(x')-1)*rcp(exp2(x')+1)
#pragma unroll
      for (int q = 0; q < 4; ++q) {
        float ei = __builtin_amdgcn_exp2f(acc[0][q]);
        float ef = __builtin_amdgcn_exp2f(acc[1][q]);
        float eg = __builtin_amdgcn_exp2f(acc[2][q]);
        float eo = __builtin_amdgcn_exp2f(acc[3][q]);
        float fv  = __builtin_amdgcn_rcpf(1.0f + ef);
        float rig = __builtin_amdgcn_rcpf((1.0f + ei) * (1.0f + eg));
        float ig  = (eg - 1.0f) * rig;
        float cn  = fv * c[rf][q] + ig;
        float ec  = __builtin_amdgcn_exp2f(cn * TWOLOG2E);
        float rho = __builtin_amdgcn_rcpf((1.0f + eo) * (1.0f + ec));
        float hn  = (ec - 1.0f) * rho;
        bool act = (int)((dgp[rf] >> (8 * q)) & 255u) > t;
        c[rf][q] = act ? cn : c[rf][q];
        u32 word = hpk[rf][q >> 1];
        u16 oldv = (u16)(word >> ((q & 1) * 16));
        u16 nh = act ? f2bf(hn) : oldv;
        hpk[rf][q >> 1] = (q & 1) ? ((word & 0x0000FFFFu) | ((u32)nh << 16))
                                  : ((word & 0xFFFF0000u) | (u32)nh);
        Hn[(rf * 16 + g4 * 4 + q) * 136 + w16 + l15] = nh;   // h(t) commit
      }
    }
    __syncthreads();   // one barrier/step: Xl/Hl[nxt] complete
    cur = nxt;
  }

  // final h is in Hl[cur]
  const u16* Hf = &Hl[cur][0];

  // out = (h @ W_lin^T) / in_norm + b_lin   (wave w owns out cols 16w..16w+15)
  short8 wl[4];
#pragma unroll
  for (int kk = 0; kk < 4; ++kk)
    wl[kk] = *(const short8*)(wlinb + (size_t)(w16 + l15) * 128 + kk * 32 + g4 * 8);
  float blv = blin[w16 + l15];
#pragma unroll
  for (int half = 0; half < 2; ++half) {
    f32x4 a2[4] = {};
#pragma unroll
    for (int kk = 0; kk < 4; ++kk)
#pragma unroll
      for (int r = 0; r < 4; ++r) {
        short8 ah = *(const short8*)(&Hf[((half * 4 + r) * 16 + l15) * 136 + kk * 32 + g4 * 8]);
        a2[r] = __builtin_amdgcn_mfma_f32_16x16x32_bf16(ah, wl[kk], a2[r], 0, 0, 0);
      }
#pragma unroll
    for (int r = 0; r < 4; ++r)
#pragma unroll
      for (int q = 0; q < 4; ++q) {
        int nl = (half * 4 + r) * 16 + g4 * 4 + q;
        int g = gidl[nl];
        out[(size_t)g * 128 + w16 + l15] = a2[r][q] / inorm[g] + blv;
      }
  }
}

extern "C" void kernel_launch(void* const* d_in, const int* in_sizes, int n_in,
                              void* d_out, int out_size, void* d_ws, size_t ws_size,
                              hipStream_t stream) {
  const float* feat    = (const float*)d_in[0];
  const float* in_norm = (const float*)d_in[1];
  const float* out_nrm = (const float*)d_in[2];
  const float* W_ih    = (const float*)d_in[3];
  const float* W_hh    = (const float*)d_in[4];
  const float* b_ih    = (const float*)d_in[5];
  const float* b_hh    = (const float*)d_in[6];
  const float* W_lin   = (const float*)d_in[7];
  const float* b_lin   = (const float*)d_in[8];
  const int* neighbors = (const int*)d_in[9];
  const int* degrees   = (const int*)d_in[10];
  float* out = (float*)d_out;

  char* ws = (char*)d_ws;
  u16* msg    = (u16*)(ws);                 // 51,200,000 B
  u16* wihb   = (u16*)(ws + 51200000);      //    131,072 B
  u16* whhb   = (u16*)(ws + 51331072);      //    131,072 B
  u16* wlinb  = (u16*)(ws + 51462144);      //     32,768 B
  float* bsum = (float*)(ws + 51494912);    //      2,048 B
  int* perm   = (int*)(ws + 51496960);      //    800,000 B
  int* hist   = (int*)(ws + 52296960);      // 64 ints
  int* basep  = hist + 64;                  // 33 ints
  if (ws_size < 52297600) return;           // need ~52.3 MB scratch

  hipMemsetAsync(hist, 0, 64 * 4, stream);
  k_prep_msg<<<12500, 256, 0, stream>>>(feat, out_nrm, msg);
  k_prep_w<<<578, 256, 0, stream>>>(W_ih, W_hh, W_lin, b_ih, b_hh, wihb, whhb, wlinb, bsum);
  k_hist<<<782, 256, 0, stream>>>(degrees, hist, NN);
  k_scan<<<1, 1, 0, stream>>>(hist, basep);
  k_scatter<<<782, 256, 0, stream>>>(degrees, basep, perm, NN);
  k_main<<<NWG, 512, 0, stream>>>(msg, wihb, whhb, wlinb, bsum, b_lin, in_norm,
                                  neighbors, degrees, perm, out);
}

// Round 9
// 1059.438 us; speedup vs baseline: 2.3569x; 2.3569x over previous
//
#include <hip/hip_runtime.h>

#define NN 200000
#define NB 64
#define NWG (NN / NB)   // 3125

typedef unsigned short u16;
typedef unsigned int u32;
typedef __attribute__((ext_vector_type(8))) short short8;
typedef __attribute__((ext_vector_type(4))) float f32x4;

#define LOG2E 1.4426950408889634f
#define TWOLOG2E 2.8853900817779268f

__device__ __forceinline__ u16 f2bf(float x) {
  u32 u = __float_as_uint(x);
  u += 0x7FFFu + ((u >> 16) & 1u);
  return (u16)(u >> 16);
}

// async global->LDS, 16B per lane; LDS dest = wave-uniform base + lane*16
typedef __attribute__((address_space(3))) unsigned int lds_u32_t;
typedef const __attribute__((address_space(1))) unsigned int glb_u32_t;
__device__ __forceinline__ void gload16(const void* g, void* l) {
  __builtin_amdgcn_global_load_lds((glb_u32_t*)g, (lds_u32_t*)l, 16, 0, 0);
}

// msg[n][k] = bf16(feat[n][k] / out_norm[n]); 16 threads per row, 8 elems each
__global__ void k_prep_msg(const float* __restrict__ feat, const float* __restrict__ onorm,
                           u16* __restrict__ msg) {
  int i = blockIdx.x * 256 + threadIdx.x;   // 3,200,000 total, exact
  int row = i >> 4, c8 = (i & 15) * 8;
  const float4 a = *(const float4*)(feat + (size_t)row * 128 + c8);
  const float4 b = *(const float4*)(feat + (size_t)row * 128 + c8 + 4);
  float s = 1.0f / onorm[row];
  short8 v = { (short)f2bf(a.x * s), (short)f2bf(a.y * s), (short)f2bf(a.z * s), (short)f2bf(a.w * s),
               (short)f2bf(b.x * s), (short)f2bf(b.y * s), (short)f2bf(b.z * s), (short)f2bf(b.w * s) };
  *(short8*)(msg + (size_t)row * 128 + c8) = v;
}

// Weights with the gate nonlinearity scale FOLDED IN:
//  gates i,f,o: x * -log2(e)  (sigmoid via exp2);  gate g: x * 2*log2(e)
__global__ void k_prep_w(const float* __restrict__ Wih, const float* __restrict__ Whh,
                         const float* __restrict__ Wlin, const float* __restrict__ bih,
                         const float* __restrict__ bhh, u16* __restrict__ wihb,
                         u16* __restrict__ whhb, u16* __restrict__ wlinb,
                         float* __restrict__ bsum) {
  int i = blockIdx.x * 256 + threadIdx.x;   // 147,968 total, exact
  if (i < 65536) {
    int gate = i >> 14;
    float s = (gate == 2) ? TWOLOG2E : -LOG2E;
    wihb[i] = f2bf(Wih[i] * s);
  } else if (i < 131072) {
    int j = i - 65536;
    int gate = j >> 14;
    float s = (gate == 2) ? TWOLOG2E : -LOG2E;
    whhb[j] = f2bf(Whh[j] * s);
  } else if (i < 147456) {
    wlinb[i - 131072] = f2bf(Wlin[i - 131072]);
  } else {
    int j = i - 147456;   // 0..511
    float s = ((j >> 7) == 2) ? TWOLOG2E : -LOG2E;
    bsum[j] = (bih[j] + bhh[j]) * s;
  }
}

__global__ void k_hist(const int* __restrict__ degs, int* __restrict__ hist, int n) {
  __shared__ int lh[33];
  if (threadIdx.x < 33) lh[threadIdx.x] = 0;
  __syncthreads();
  int i = blockIdx.x * 256 + threadIdx.x;
  if (i < n) atomicAdd(&lh[degs[i]], 1);
  __syncthreads();
  if (threadIdx.x < 33 && lh[threadIdx.x]) atomicAdd(&hist[threadIdx.x], lh[threadIdx.x]);
}

__global__ void k_scan(const int* __restrict__ hist, int* __restrict__ basep) {
  if (threadIdx.x == 0 && blockIdx.x == 0) {
    int a = 0;
    for (int d = 32; d >= 1; --d) { basep[d] = a; a += hist[d]; }
    basep[0] = a;
  }
}

__global__ void k_scatter(const int* __restrict__ degs, int* __restrict__ basep,
                          int* __restrict__ perm, int n) {
  __shared__ int lh[33], lbase[33], lc[33];
  int t = threadIdx.x;
  if (t < 33) { lh[t] = 0; lc[t] = 0; }
  __syncthreads();
  int i = blockIdx.x * 256 + t;
  int d = (i < n) ? degs[i] : 0;
  if (i < n) atomicAdd(&lh[d], 1);
  __syncthreads();
  if (t < 33 && lh[t]) lbase[t] = atomicAdd(&basep[t], lh[t]);
  __syncthreads();
  if (i < n) { int r = atomicAdd(&lc[d], 1); perm[lbase[d] + r] = i; }
}

// R6 base (proven 1069 us, no spill) + register-negative changes only:
//  - X tile staged via global_load_lds (linear stride-128, XOR-chunk swizzle
//    pre-applied on the per-lane GLOBAL address; reads unswizzle with same XOR)
//  - h carry packed to hpk[4][2] (-8 regs); h-commit spread into each pass
__global__ __launch_bounds__(512, 2) void k_main(
    const u16* __restrict__ msg, const u16* __restrict__ wihb,
    const u16* __restrict__ whhb, const u16* __restrict__ wlinb,
    const float* __restrict__ bsum, const float* __restrict__ blin,
    const float* __restrict__ inorm, const int* __restrict__ nbrs,
    const int* __restrict__ degs, const int* __restrict__ perm,
    float* __restrict__ out) {
  __shared__ alignas(16) u16 Xl[2][64 * 128];   // linear (DMA dest), 2x16384 B
  __shared__ alignas(16) u16 Hl[2][64 * 136];   // padded, 2x17408 B
  __shared__ int gidl[64];                       // total ~66.3 KB

  const int tid = threadIdx.x;
  const int w = tid >> 6;
  const int lane = tid & 63;
  const int l15 = lane & 15;
  const int g4 = lane >> 4;
  const int w16 = w * 16;
  const int gr = tid >> 4;                        // this thread's gather rows: gr, gr+32
  const int xc8 = (((tid & 15) ^ (gr & 15)) * 8); // swizzled source chunk (u16 units)
  const int wbase = w * 512;                      // wave's DMA dest base in Xl (u16)
  const int base = blockIdx.x * NB;

  if (tid < NB) gidl[tid] = perm[base + tid];
  // zero Hl[0] (Hl[1] fully written before first read)
  {
    u32* hz = (u32*)Hl[0];
#pragma unroll
    for (int s = 0; s < 8; ++s) hz[tid + s * 512] = 0;
    if (tid < 256) hz[tid + 4096] = 0;
  }
  __syncthreads();

  const int gid0 = gidl[gr], gid1 = gidl[gr + 32];
  const int* nb0 = nbrs + (size_t)gid0 * 32;
  const int* nb1 = nbrs + (size_t)gid1 * 32;

  // stage X(0) via DMA (swizzled source); completes at the next barrier
  {
    int i0 = nb0[0], i1 = nb1[0];
    gload16(msg + (size_t)i0 * 128 + xc8, &Xl[0][wbase]);
    gload16(msg + (size_t)i1 * 128 + xc8, &Xl[0][4096 + wbase]);
  }
  int ni0 = 0, ni1 = 0;
  if (degs[gidl[0]] > 1) { ni0 = nb0[1]; ni1 = nb1[1]; }

  // per-wave B fragments (row-major W rows are exactly the B-frag layout)
  short8 fih[4][4], fhh[4][4];
#pragma unroll
  for (int g = 0; g < 4; ++g)
#pragma unroll
    for (int kk = 0; kk < 4; ++kk) {
      size_t o = (size_t)(g * 128 + w16 + l15) * 128 + kk * 32 + g4 * 8;
      fih[g][kk] = *(const short8*)(wihb + o);
      fhh[g][kk] = *(const short8*)(whhb + o);
    }
  float bias[4];
#pragma unroll
  for (int g = 0; g < 4; ++g) bias[g] = bsum[g * 128 + w16 + l15];

  u32 dgp[4];
#pragma unroll
  for (int r = 0; r < 4; ++r) {
    u32 p = 0;
#pragma unroll
    for (int q = 0; q < 4; ++q) p |= ((u32)degs[gidl[r * 16 + g4 * 4 + q]]) << (8 * q);
    dgp[r] = p;
  }
  const int maxdeg = degs[gidl[0]];   // sorted descending -> first is WG max

  // X-read swizzle offsets (logical chunk kk*4+g4 -> physical ^ l15), u16 units
  int xsw[4];
#pragma unroll
  for (int kk = 0; kk < 4; ++kk) xsw[kk] = ((kk * 4 + g4) ^ l15) * 8;

  float c[4][4] = {};
  u32 hpk[4][2] = {};   // packed bf16 h carry
  __syncthreads();       // X(0) staged, Hl[0] zeroed, gidl ready

  int cur = 0;
  for (int t = 0; t < maxdeg; ++t) {
    const int nxt = cur ^ 1;
    // stage X(t+1) via DMA into the alternate buffer (safe: all waves passed
    // the barrier ending step t-1, nobody reads Xl[nxt] this step)
    if (t + 1 < maxdeg) {
      gload16(msg + (size_t)ni0 * 128 + xc8, &Xl[nxt][wbase]);
      gload16(msg + (size_t)ni1 * 128 + xc8, &Xl[nxt][4096 + wbase]);
    }
    if (t + 2 < maxdeg) { ni0 = nb0[t + 2]; ni1 = nb1[t + 2]; }

    const u16* Xc = &Xl[cur][0];
    const u16* Hc = &Hl[cur][0];
    u16* Hn = &Hl[nxt][0];

    // two row-passes; within a pass: X phase then H phase (8 accumulators,
    // reuse distance 4 — R6's proven order); h-commit inside each pass
#pragma unroll
    for (int rp = 0; rp < 2; ++rp) {
      f32x4 acc[2][4];
#pragma unroll
      for (int r = 0; r < 2; ++r)
#pragma unroll
        for (int g = 0; g < 4; ++g) acc[r][g] = (f32x4){bias[g], bias[g], bias[g], bias[g]};

#pragma unroll
      for (int rf = 0; rf < 2; ++rf) {
        short8 ax[4];
#pragma unroll
        for (int kk = 0; kk < 4; ++kk)
          ax[kk] = *(const short8*)(&Xc[(rp * 32 + rf * 16 + l15) * 128 + xsw[kk]]);
#pragma unroll
        for (int kk = 0; kk < 4; ++kk)
#pragma unroll
          for (int g = 0; g < 4; ++g)
            acc[rf][g] = __builtin_amdgcn_mfma_f32_16x16x32_bf16(ax[kk], fih[g][kk], acc[rf][g], 0, 0, 0);
      }
#pragma unroll
      for (int rf = 0; rf < 2; ++rf) {
        short8 ah[4];
#pragma unroll
        for (int kk = 0; kk < 4; ++kk)
          ah[kk] = *(const short8*)(&Hc[(rp * 32 + rf * 16 + l15) * 136 + kk * 32 + g4 * 8]);
#pragma unroll
        for (int kk = 0; kk < 4; ++kk)
#pragma unroll
          for (int g = 0; g < 4; ++g)
            acc[rf][g] = __builtin_amdgcn_mfma_f32_16x16x32_bf16(ah[kk], fhh[g][kk], acc[rf][g], 0, 0, 0);
      }

      // epilogue: preacts pre-scaled (i,f,o by -log2e; g by 2log2e)
      //  sig(x)=rcp(1+exp2(x')); tanh(x)=(exp2(x')-1)*rcp(exp2(x')+1)
#pragma unroll
      for (int r = 0; r < 2; ++r) {
        const int rr = rp * 2 + r;
#pragma unroll
        for (int q = 0; q < 4; ++q) {
          float ei = __builtin_amdgcn_exp2f(acc[r][0][q]);
          float ef = __builtin_amdgcn_exp2f(acc[r][1][q]);
          float eg = __builtin_amdgcn_exp2f(acc[r][2][q]);
          float eo = __builtin_amdgcn_exp2f(acc[r][3][q]);
          float fv  = __builtin_amdgcn_rcpf(1.0f + ef);
          float rig = __builtin_amdgcn_rcpf((1.0f + ei) * (1.0f + eg));
          float ig  = (eg - 1.0f) * rig;
          float cn  = fv * c[rr][q] + ig;
          float ec  = __builtin_amdgcn_exp2f(cn * TWOLOG2E);
          float rho = __builtin_amdgcn_rcpf((1.0f + eo) * (1.0f + ec));
          float hn  = (ec - 1.0f) * rho;
          bool act = (int)((dgp[rr] >> (8 * q)) & 255u) > t;
          c[rr][q] = act ? cn : c[rr][q];
          u32 word = hpk[rr][q >> 1];
          u16 oldv = (u16)(word >> ((q & 1) * 16));
          u16 nh = act ? f2bf(hn) : oldv;
          hpk[rr][q >> 1] = (q & 1) ? ((word & 0x0000FFFFu) | ((u32)nh << 16))
                                    : ((word & 0xFFFF0000u) | (u32)nh);
          Hn[(rr * 16 + g4 * 4 + q) * 136 + w16 + l15] = nh;   // h(t) commit
        }
      }
    }
    __syncthreads();   // one barrier/step (drains DMA vmcnt + lgkm per HIP semantics)
    cur = nxt;
  }

  // final h is in Hl[cur]
  const u16* Hf = &Hl[cur][0];

  // out = (h @ W_lin^T) / in_norm + b_lin   (wave w owns out cols 16w..16w+15)
  short8 wl[4];
#pragma unroll
  for (int kk = 0; kk < 4; ++kk)
    wl[kk] = *(const short8*)(wlinb + (size_t)(w16 + l15) * 128 + kk * 32 + g4 * 8);
  f32x4 a2[4] = {};
#pragma unroll
  for (int kk = 0; kk < 4; ++kk)
#pragma unroll
    for (int r = 0; r < 4; ++r) {
      short8 ah = *(const short8*)(&Hf[(r * 16 + l15) * 136 + kk * 32 + g4 * 8]);
      a2[r] = __builtin_amdgcn_mfma_f32_16x16x32_bf16(ah, wl[kk], a2[r], 0, 0, 0);
    }
  float blv = blin[w16 + l15];
#pragma unroll
  for (int r = 0; r < 4; ++r)
#pragma unroll
    for (int q = 0; q < 4; ++q) {
      int nl = r * 16 + g4 * 4 + q;
      int g = gidl[nl];
      out[(size_t)g * 128 + w16 + l15] = a2[r][q] / inorm[g] + blv;
    }
}

extern "C" void kernel_launch(void* const* d_in, const int* in_sizes, int n_in,
                              void* d_out, int out_size, void* d_ws, size_t ws_size,
                              hipStream_t stream) {
  const float* feat    = (const float*)d_in[0];
  const float* in_norm = (const float*)d_in[1];
  const float* out_nrm = (const float*)d_in[2];
  const float* W_ih    = (const float*)d_in[3];
  const float* W_hh    = (const float*)d_in[4];
  const float* b_ih    = (const float*)d_in[5];
  const float* b_hh    = (const float*)d_in[6];
  const float* W_lin   = (const float*)d_in[7];
  const float* b_lin   = (const float*)d_in[8];
  const int* neighbors = (const int*)d_in[9];
  const int* degrees   = (const int*)d_in[10];
  float* out = (float*)d_out;

  char* ws = (char*)d_ws;
  u16* msg    = (u16*)(ws);                 // 51,200,000 B
  u16* wihb   = (u16*)(ws + 51200000);      //    131,072 B
  u16* whhb   = (u16*)(ws + 51331072);      //    131,072 B
  u16* wlinb  = (u16*)(ws + 51462144);      //     32,768 B
  float* bsum = (float*)(ws + 51494912);    //      2,048 B
  int* perm   = (int*)(ws + 51496960);      //    800,000 B
  int* hist   = (int*)(ws + 52296960);      // 64 ints
  int* basep  = hist + 64;                  // 33 ints
  if (ws_size < 52297600) return;           // need ~52.3 MB scratch

  hipMemsetAsync(hist, 0, 64 * 4, stream);
  k_prep_msg<<<12500, 256, 0, stream>>>(feat, out_nrm, msg);
  k_prep_w<<<578, 256, 0, stream>>>(W_ih, W_hh, W_lin, b_ih, b_hh, wihb, whhb, wlinb, bsum);
  k_hist<<<782, 256, 0, stream>>>(degrees, hist, NN);
  k_scan<<<1, 1, 0, stream>>>(hist, basep);
  k_scatter<<<782, 256, 0, stream>>>(degrees, basep, perm, NN);
  k_main<<<NWG, 512, 0, stream>>>(msg, wihb, whhb, wlinb, bsum, b_lin, in_norm,
                                  neighbors, degrees, perm, out);
}